// Round 18
// baseline (422.146 us; speedup 1.0000x reference)
//
#include <hip/hip_runtime.h>

typedef unsigned short u16;
typedef unsigned int   u32;
typedef unsigned long long u64;
typedef __attribute__((ext_vector_type(2)))  u32  u32x2;
typedef __attribute__((ext_vector_type(4)))  float f32x4;
typedef __attribute__((ext_vector_type(16))) float f32x16;
typedef __attribute__((ext_vector_type(8)))  short b16x8;

#define T_ 256
#define B_ 32
#define V_ 32000
#define H_ 256

// fp32 -> bf16 round-to-nearest-even
__device__ __forceinline__ u16 f2bf(float f){
  union { float fv; u32 uv; } v; v.fv = f;
  return (u16)((v.uv + 0x7FFFu + ((v.uv >> 16) & 1u)) >> 16);
}
__device__ __forceinline__ float bf2f(short x){
  union { float fv; u32 uv; } c; c.uv = ((u32)(u16)x) << 16; return c.fv;
}
__device__ __forceinline__ float sigm_fast(float z){
  return __builtin_amdgcn_rcpf(1.0f + __builtin_amdgcn_exp2f(z * -1.44269504f));
}
// 16B agent-scope (cross-XCD coherent) load/store as 2x u64 atomics
__device__ __forceinline__ b16x8 ald16(const u16* p){
  union { u64 q[2]; b16x8 v; } u;
  const u64* q = (const u64*)p;
  u.q[0] = __hip_atomic_load(q,     __ATOMIC_RELAXED, __HIP_MEMORY_SCOPE_AGENT);
  u.q[1] = __hip_atomic_load(q + 1, __ATOMIC_RELAXED, __HIP_MEMORY_SCOPE_AGENT);
  return u.v;
}
__device__ __forceinline__ void ast16(u16* p, b16x8 v){
  union { u64 q[2]; b16x8 v; } u; u.v = v;
  u64* q = (u64*)p;
  __hip_atomic_store(q,     u.q[0], __ATOMIC_RELAXED, __HIP_MEMORY_SCOPE_AGENT);
  __hip_atomic_store(q + 1, u.q[1], __ATOMIC_RELAXED, __HIP_MEMORY_SCOPE_AGENT);
}

// Per-mb2 handshake: pf entry (l, m) = u32 at flags[l*1024 + m*16]
// (64 B/entry). Binary: 1 once outseq steps [0, 4m+4) from producer l
// are stored & drained (publish only after a vmcnt(0)-drained barrier).

// ---------------------------------------------------------------------------
// prep (vectorized 8x, R12-verified): decW -> bf16 ; W^T copies ; flag reset
// ---------------------------------------------------------------------------
__global__ __launch_bounds__(256)
void prep_kernel(const float* __restrict__ Wi, const float* __restrict__ Wh,
                 const float* __restrict__ decW,
                 u16* __restrict__ decWb, u16* __restrict__ wt,
                 u32* __restrict__ flags){
  if (blockIdx.x == 0){
    for (int i = threadIdx.x; i < 2048; i += 256) flags[i] = 0;
  }
  const int NDECG = (V_ * H_) / 8;                 // 1,024,000
  const int NWTG  = (4 * H_ * H_) / 8;             //    32,768
  const int g = blockIdx.x * blockDim.x + threadIdx.x;
  if (g < NDECG){
    const float* s = decW + (size_t)g * 8;
    f32x4 a = *(const f32x4*)(s);
    f32x4 b = *(const f32x4*)(s + 4);
    union { u16 h[8]; b16x8 v; } o;
    #pragma unroll
    for (int u = 0; u < 4; ++u){
      o.h[u]     = f2bf(a[u]);
      o.h[4 + u] = f2bf(b[u]);
    }
    *(b16x8*)(decWb + (size_t)g * 8) = o.v;
  } else if (g < NDECG + NWTG){
    const int j0 = (g - NDECG) * 8;
    const int m  = j0 >> 16;
    const int r  = j0 & 65535;
    const int row = r >> 8;
    const int k0  = r & 255;
    const float* src = (m == 0) ? Wh
                     : (m == 1) ? (Wi + H_ * H_)
                     : (m == 2) ? (Wh + H_ * H_)
                     :            Wi;
    union { u16 h[8]; b16x8 v; } o;
    #pragma unroll
    for (int u = 0; u < 8; ++u)
      o.h[u] = f2bf(src[(k0 + u) * H_ + row]);
    *(b16x8*)(wt + j0) = o.v;
  }
}

// xp layout (R8/R10-verified, matches swapped consumers):
//   x[t][batch m][col n] at xp[t*8192 + (m>>4)*4096 + (n>>2)*64 + (m&15)*4 + (n&3)]

// ---------------------------------------------------------------------------
// x0: swapped-operand form (R8/R10-verified). Block = one step t; 4 waves.
// ---------------------------------------------------------------------------
__global__ __launch_bounds__(256, 2)
void x0_kernel(const int* __restrict__ ids, const float* __restrict__ emb,
               const u16* __restrict__ WiT0, const float* __restrict__ bh,
               float* __restrict__ xp){
  const int tid = threadIdx.x, w = tid >> 6, l = tid & 63;
  const int lr = l & 15, lh = l >> 4;
  const int t = blockIdx.x;

  b16x8 wA[4][8];
  #pragma unroll
  for (int nt = 0; nt < 4; ++nt){
    const int col = w * 64 + nt * 16 + lr;
    #pragma unroll
    for (int ks = 0; ks < 8; ++ks)
      wA[nt][ks] = *(const b16x8*)(WiT0 + (size_t)col * H_ + ks * 32 + lh * 8);
  }

  const int b0 = ids[t * B_ + lr];
  const int b1 = ids[t * B_ + 16 + lr];
  const float* er0 = emb + (size_t)b0 * H_;
  const float* er1 = emb + (size_t)b1 * H_;

  f32x4 acc[2][4];
  #pragma unroll
  for (int nt = 0; nt < 4; ++nt){
    f32x4 bs = *(const f32x4*)(bh + w * 64 + nt * 16 + lh * 4);
    acc[0][nt] = bs;
    acc[1][nt] = bs;
  }

  #pragma unroll
  for (int ks = 0; ks < 8; ++ks){
    b16x8 e[2];
    {
      f32x4 a0 = *(const f32x4*)(er0 + ks * 32 + lh * 8);
      f32x4 a1 = *(const f32x4*)(er0 + ks * 32 + lh * 8 + 4);
      f32x4 c0 = *(const f32x4*)(er1 + ks * 32 + lh * 8);
      f32x4 c1 = *(const f32x4*)(er1 + ks * 32 + lh * 8 + 4);
      #pragma unroll
      for (int i2 = 0; i2 < 4; ++i2){
        e[0][i2] = (short)f2bf(a0[i2]); e[0][4 + i2] = (short)f2bf(a1[i2]);
        e[1][i2] = (short)f2bf(c0[i2]); e[1][4 + i2] = (short)f2bf(c1[i2]);
      }
    }
    #pragma unroll
    for (int nt = 0; nt < 4; ++nt){
      acc[0][nt] = __builtin_amdgcn_mfma_f32_16x16x32_bf16(wA[nt][ks], e[0], acc[0][nt], 0, 0, 0);
      acc[1][nt] = __builtin_amdgcn_mfma_f32_16x16x32_bf16(wA[nt][ks], e[1], acc[1][nt], 0, 0, 0);
    }
  }
  #pragma unroll
  for (int mt = 0; mt < 2; ++mt)
    #pragma unroll
    for (int nt = 0; nt < 4; ++nt)
      *(f32x4*)(xp + (size_t)t * 8192 + mt * 4096 + w * 1024 + nt * 256 + lh * 64 + lr * 4)
          = acc[mt][nt];
}

// ---------------------------------------------------------------------------
// mega: blocks 0-1 = rec; blocks 2..1025 = dec (A-resident, R16-verified).
// NEW (R18): rec mid-iteration barriers are raw s_barrier + lgkmcnt(0) only
// — outseq sc1 stores float across them (drained only at iteration end,
// where the publish needs visibility). HK/m139 pattern.
// ---------------------------------------------------------------------------
__global__ __launch_bounds__(512, 1)
void mega_kernel(const u16* __restrict__ wt, const float* __restrict__ xp,
                 const float* __restrict__ bh,
                 u16* __restrict__ outseq, float* __restrict__ hid,
                 const u16* __restrict__ decWb, const float* __restrict__ decB,
                 float* __restrict__ out, u32* __restrict__ flags){
  __shared__ u16 smu[65536];                        // 128 KiB union
  char* smem = (char*)smu;
  const int tid = threadIdx.x, w = tid >> 6, l = tid & 63;
  const int bid = blockIdx.x;

  if (bid < 2){
    // =============== rec: both layers, batch rows [bid*16, +16) ===========
    const int lr = l & 15, lh = l >> 4;

    const u16* whT0 = wt;
    const u16* wiT1 = wt + 65536;
    const u16* whT1 = wt + 131072;

    b16x8 wH0[2][8], wI1[2][8], wH1[2][8];
    #pragma unroll
    for (int nt = 0; nt < 2; ++nt){
      const int col = w * 32 + nt * 16 + lr;
      #pragma unroll
      for (int ks = 0; ks < 8; ++ks){
        wH0[nt][ks] = *(const b16x8*)(whT0 + (size_t)col * H_ + ks * 32 + lh * 8);
        wI1[nt][ks] = *(const b16x8*)(wiT1 + (size_t)col * H_ + ks * 32 + lh * 8);
        wH1[nt][ks] = *(const b16x8*)(whT1 + (size_t)col * H_ + ks * 32 + lh * 8);
      }
    }
    f32x4 bs1[2];
    #pragma unroll
    for (int nt = 0; nt < 2; ++nt)
      bs1[nt] = *(const f32x4*)(bh + H_ + w * 32 + nt * 16 + lh * 4);

    int ra[8];
    #pragma unroll
    for (int ks = 0; ks < 8; ++ks)
      ra[ks] = lr * 512 + ((ks * 64 + lh * 16) ^ ((lr & 7) << 4));

    int wrh[2];
    #pragma unroll
    for (int nt = 0; nt < 2; ++nt)
      wrh[nt] = lr * 512 + ((w * 64 + nt * 32 + lh * 8) ^ ((lr & 7) << 4));

    const int srow = tid >> 5, scolb = (tid & 31) * 16;
    const int sa = srow * 512 + (scolb ^ ((srow & 7) << 4));
    const size_t sgbase = (size_t)(bid * 16 + srow) * H_ + (tid & 31) * 8;

    const int xoff = bid * 4096 + w * 512 + lh * 64 + lr * 4;

    u32* pfmine = flags + (size_t)bid * 1024;       // entry m at +m*16

    { u32* z = (u32*)smem;
      for (int i = tid; i < 8192; i += 512) z[i] = 0; }   // h0[-1], h1[-1] = 0

    f32x4 xc0, xc1, xn0, xn1;
    xc0 = *(const f32x4*)(xp + xoff);
    xc1 = *(const f32x4*)(xp + xoff + 256);
    __syncthreads();

#define PACKW(DST, ADDR, V0, V1, V2, V3)                                        \
  { u32x2 pk;                                                                   \
    pk[0] = (u32)f2bf(V0) | ((u32)f2bf(V1) << 16);                              \
    pk[1] = (u32)f2bf(V2) | ((u32)f2bf(V3) << 16);                              \
    *(u32x2*)((DST) + (ADDR)) = pk; }

#define STEP(PAR, S, FULLDRAIN)                                                 \
  {                                                                             \
    const char* rb0 = smem + (PAR) * 8192;                                      \
    const char* rb1 = smem + 16384 + (1 - (PAR)) * 8192;                        \
    if ((S) >= 2){                                                              \
      b16x8 v = *(const b16x8*)(rb1 + sa);                                      \
      ast16(outseq + (size_t)((S) - 2) * 8192 + sgbase, v);                     \
    }                                                                           \
    f32x4 c0 = (f32x4){}, c1 = (f32x4){};                                       \
    f32x4 d0 = bs1[0], d1 = bs1[1];                                             \
    _Pragma("unroll")                                                           \
    for (int ks = 0; ks < 8; ++ks){                                             \
      b16x8 a = *(const b16x8*)(rb0 + ra[ks]);                                  \
      c0 = __builtin_amdgcn_mfma_f32_16x16x32_bf16(wH0[0][ks], a, c0, 0, 0, 0); \
      c1 = __builtin_amdgcn_mfma_f32_16x16x32_bf16(wH0[1][ks], a, c1, 0, 0, 0); \
      d0 = __builtin_amdgcn_mfma_f32_16x16x32_bf16(wI1[0][ks], a, d0, 0, 0, 0); \
      d1 = __builtin_amdgcn_mfma_f32_16x16x32_bf16(wI1[1][ks], a, d1, 0, 0, 0); \
    }                                                                           \
    { const float* pn = xp + (size_t)(((S) < 255) ? (S) + 1 : 255) * 8192 + xoff; \
      xn0 = *(const f32x4*)(pn);                                                \
      xn1 = *(const f32x4*)(pn + 256); }                                        \
    { char* wb0 = smem + (1 - (PAR)) * 8192;                                    \
      PACKW(wb0, wrh[0], sigm_fast(c0[0] + xc0[0]), sigm_fast(c0[1] + xc0[1]),  \
                         sigm_fast(c0[2] + xc0[2]), sigm_fast(c0[3] + xc0[3]))  \
      PACKW(wb0, wrh[1], sigm_fast(c1[0] + xc1[0]), sigm_fast(c1[1] + xc1[1]),  \
                         sigm_fast(c1[2] + xc1[2]), sigm_fast(c1[3] + xc1[3]))  \
    }                                                                           \
    if ((S) >= 1){                                                              \
      _Pragma("unroll")                                                         \
      for (int ks = 0; ks < 8; ++ks){                                           \
        b16x8 a = *(const b16x8*)(rb1 + ra[ks]);                                \
        d0 = __builtin_amdgcn_mfma_f32_16x16x32_bf16(wH1[0][ks], a, d0, 0, 0, 0); \
        d1 = __builtin_amdgcn_mfma_f32_16x16x32_bf16(wH1[1][ks], a, d1, 0, 0, 0); \
      }                                                                         \
      char* wb1 = smem + 16384 + (PAR) * 8192;                                  \
      PACKW(wb1, wrh[0], sigm_fast(d0[0]), sigm_fast(d0[1]),                    \
                         sigm_fast(d0[2]), sigm_fast(d0[3]))                    \
      PACKW(wb1, wrh[1], sigm_fast(d1[0]), sigm_fast(d1[1]),                    \
                         sigm_fast(d1[2]), sigm_fast(d1[3]))                    \
    }                                                                           \
    xc0 = xn0; xc1 = xn1;                                                       \
    if (FULLDRAIN){                                                             \
      asm volatile("s_waitcnt vmcnt(0) lgkmcnt(0)" ::: "memory");               \
    } else {                                                                    \
      asm volatile("s_waitcnt lgkmcnt(0)" ::: "memory");                        \
    }                                                                           \
    __builtin_amdgcn_s_barrier();                                               \
  }

    for (int s2 = 0; s2 < 128; ++s2){
      const int s = s2 * 2;
      STEP(0, s,     0)                     // lgkm-only barrier: stores float
      STEP(1, s + 1, 1)                     // full drain: publish-safe
      // After the drained barrier, outseq steps <= 2*s2-1 are globally
      // visible via sc1. Entry m needs steps <= 4m+3: ready when s2 even
      // and >= 2, m = s2/2 - 1. One 64B-line store, RELAXED.
      if (tid == 0 && (s2 & 1) == 0 && s2 >= 2)
        __hip_atomic_store(pfmine + (s2 / 2 - 1) * 16, 1u, __ATOMIC_RELAXED,
                           __HIP_MEMORY_SCOPE_AGENT);
    }
#undef STEP

    // epilogue: h0[255] in h0 buf0; h1[254] in h1 buf1; compute h1[255]
    {
      { b16x8 v = *(const b16x8*)(smem + 16384 + 8192 + sa);
        ast16(outseq + (size_t)254 * 8192 + sgbase, v); }

      f32x4 d0 = bs1[0], d1 = bs1[1];
      #pragma unroll
      for (int ks = 0; ks < 8; ++ks){
        b16x8 a0 = *(const b16x8*)(smem + ra[ks]);
        b16x8 a1 = *(const b16x8*)(smem + 16384 + 8192 + ra[ks]);
        d0 = __builtin_amdgcn_mfma_f32_16x16x32_bf16(wI1[0][ks], a0, d0, 0, 0, 0);
        d1 = __builtin_amdgcn_mfma_f32_16x16x32_bf16(wI1[1][ks], a0, d1, 0, 0, 0);
        d0 = __builtin_amdgcn_mfma_f32_16x16x32_bf16(wH1[0][ks], a1, d0, 0, 0, 0);
        d1 = __builtin_amdgcn_mfma_f32_16x16x32_bf16(wH1[1][ks], a1, d1, 0, 0, 0);
      }
      { char* wb1 = smem + 16384;
        PACKW(wb1, wrh[0], sigm_fast(d0[0]), sigm_fast(d0[1]),
                           sigm_fast(d0[2]), sigm_fast(d0[3]))
        PACKW(wb1, wrh[1], sigm_fast(d1[0]), sigm_fast(d1[1]),
                           sigm_fast(d1[2]), sigm_fast(d1[3]))
      }
      __syncthreads();

      b16x8 h1v = *(const b16x8*)(smem + 16384 + sa);
      b16x8 h0v = *(const b16x8*)(smem + sa);
      ast16(outseq + (size_t)255 * 8192 + sgbase, h1v);
      float* hd0 = hid + sgbase;
      float* hd1 = hid + 8192 + sgbase;
      #pragma unroll
      for (int j = 0; j < 8; ++j){
        hd0[j] = bf2f(h0v[j]);
        hd1[j] = bf2f(h1v[j]);
      }
      __syncthreads();                // drains the final ast16 stores (vmcnt 0)
      if (tid == 0)
        __hip_atomic_store(pfmine + 63 * 16, 1u, __ATOMIC_RELAXED,
                           __HIP_MEMORY_SCOPE_AGENT);
    }
#undef PACKW
  } else {
    // =============== dec: A-resident persistent tiles (R16-verified) ======
    const int la = l & 31, hi = l >> 5;
    const int wm = w >> 2, wn = w & 3;              // wm 0..1, wn 0..3

    const int idx  = bid - 2;                       // 0..1023
    const int mb2  = idx >> 4;                      // 0..63 (128-row A half)
    const int slot = idx & 15;                      // 0..15

    // wait on THIS mb2's two private flag lines
    if (tid == 0){
      const u32* p0 = flags + (size_t)mb2 * 16;
      const u32* p1 = flags + 1024 + (size_t)mb2 * 16;
      for (;;){
        u32 a = __hip_atomic_load(p0, __ATOMIC_RELAXED, __HIP_MEMORY_SCOPE_AGENT);
        u32 b = __hip_atomic_load(p1, __ATOMIC_RELAXED, __HIP_MEMORY_SCOPE_AGENT);
        if (a & b) break;
        __builtin_amdgcn_s_sleep(16);
      }
    }
    __syncthreads();

    // ---- stage A half-tile (once): rows mb2*128 + rA0 + 16j, full K ----
    {
      const int cA  = tid & 31;                     // 16B chunk 0..31
      const int rA0 = tid >> 5;                     // 0..15
      #pragma unroll
      for (int j = 0; j < 8; ++j){
        const int row = rA0 + 16 * j;
        b16x8 v = ald16(outseq + (size_t)(mb2 * 128 + row) * H_ + cA * 8);
        *(b16x8*)(smem + row * 512 + ((cA ^ (row & 7)) << 4)) = v;
      }
    }

    // ---- B staging (per kk chunk of K=64), double-buffered ----
    const int srowB = tid >> 3;                     // 0..63
    const int scB   = tid & 7;                      // 0..7
    const int scxB  = scB ^ (srowB & 7);
    const int slB   = srowB * 128 + scxB * 16;
    b16x8 rB[4];
#define BLOADS(NB, KK)                                                          \
  do { const size_t gB = ((size_t)((NB) * 256 + srowB)) * H_ + scB * 8;         \
    _Pragma("unroll")                                                           \
    for (int s5 = 0; s5 < 4; ++s5)                                              \
      rB[s5] = *(const b16x8*)(decWb + gB + (size_t)s5 * 64 * H_ + (KK) * 64);  \
  } while (0)
#define BSWRITE(BUF)                                                            \
  do { _Pragma("unroll")                                                        \
    for (int s5 = 0; s5 < 4; ++s5)                                              \
      *(b16x8*)(smem + 65536 + (BUF) * 32768 + s5 * 8192 + slB) = rB[s5];       \
  } while (0)

    // fragment read geometry
    const int aRow = wm * 64 + la;                  // + mt*32 (A rows 0..127)
    const int bRow = wn * 64 + la;                  // + nt*32 (B rows 0..255)
    int fOffB[4];
    #pragma unroll
    for (int ks = 0; ks < 4; ++ks)
      fOffB[ks] = ((ks * 32 + hi * 16) ^ ((la & 7) << 4));

    BLOADS(slot, 0);
    for (int nb = slot; nb < 125; nb += 16){
      f32x16 acc[2][2];
      #pragma unroll
      for (int mt = 0; mt < 2; ++mt)
        #pragma unroll
        for (int nt = 0; nt < 2; ++nt)
          acc[mt][nt] = (f32x16){};

      #pragma unroll
      for (int kk = 0; kk < 4; ++kk){
        BSWRITE(kk & 1);
        if (kk < 3){
          BLOADS(nb, kk + 1);
        } else if (nb + 16 < 125){
          BLOADS(nb + 16, 0);                       // cross-tile prefetch
        }
        __syncthreads();
        const char* bufB = smem + 65536 + (kk & 1) * 32768;
        #pragma unroll
        for (int ks = 0; ks < 4; ++ks){
          b16x8 aF[2], bF[2];
          #pragma unroll
          for (int mt = 0; mt < 2; ++mt){
            const int row = aRow + mt * 32;
            const int c   = kk * 8 + ks * 2 + hi;         // 16B chunk = k/8
            aF[mt] = *(const b16x8*)(smem + row * 512 + ((c ^ (row & 7)) << 4));
          }
          #pragma unroll
          for (int nt = 0; nt < 2; ++nt)
            bF[nt] = *(const b16x8*)(bufB + (bRow + nt * 32) * 128 + fOffB[ks]);
          #pragma unroll
          for (int mt = 0; mt < 2; ++mt)
            #pragma unroll
            for (int nt = 0; nt < 2; ++nt)
              acc[mt][nt] = __builtin_amdgcn_mfma_f32_32x32x16_bf16(aF[mt], bF[nt], acc[mt][nt], 0, 0, 0);
        }
        __syncthreads();
      }

      // epilogue: bias + NT store (C layout: col=la, row=(r&3)+8*(r>>2)+4*hi)
      #pragma unroll
      for (int nt = 0; nt < 2; ++nt){
        const int colg = nb * 256 + wn * 64 + nt * 32 + la;
        const float bias = decB[colg];
        #pragma unroll
        for (int mt = 0; mt < 2; ++mt){
          const int rowb = mb2 * 128 + wm * 64 + mt * 32 + hi * 4;
          #pragma unroll
          for (int r = 0; r < 16; ++r){
            const int rowg = rowb + (r & 3) + 8 * (r >> 2);
            __builtin_nontemporal_store(acc[mt][nt][r] + bias,
                                        &out[(size_t)rowg * V_ + colg]);
          }
        }
      }
    }
#undef BLOADS
#undef BSWRITE
  }
}

// ---------------------------------------------------------------------------
extern "C" void kernel_launch(void* const* d_in, const int* in_sizes, int n_in,
                              void* d_out, int out_size, void* d_ws, size_t ws_size,
                              hipStream_t stream){
  const int*   ids  = (const int*)  d_in[0];
  const float* emb  = (const float*)d_in[1];
  const float* Wi   = (const float*)d_in[2];
  const float* Wh   = (const float*)d_in[3];
  const float* bh   = (const float*)d_in[4];
  const float* decW = (const float*)d_in[5];
  const float* decB = (const float*)d_in[6];
  float* out = (float*)d_out;

  char* ws = (char*)d_ws;
  u16*  decWb  = (u16*)(ws);                       // 16,384,000 B
  u16*  wt     = (u16*)(ws + 16384000);            //    524,288 B
  u16*  outseq = (u16*)(ws + 16908288);            //  4,194,304 B
  float* xp    = (float*)(ws + 21102592);          //  8,388,608 B
  u32*  flags  = (u32*)(ws + 29491200);            //      8,192 B (pf[2][64])

  float* hid = out + (size_t)T_ * B_ * V_;         // [L][B][H] fp32 tail of d_out

  prep_kernel<<<4128, 256, 0, stream>>>(Wi, Wh, decW, decWb, wt, flags);
  x0_kernel<<<256, 256, 0, stream>>>(ids, emb, wt + 3 * H_ * H_, bh, xp);
  mega_kernel<<<1026, 512, 0, stream>>>(wt, xp, bh, outseq, hid,
                                        decWb, decB, out, flags);
}

// Round 19
// 414.394 us; speedup vs baseline: 1.0187x; 1.0187x over previous
//
#include <hip/hip_runtime.h>

typedef unsigned short u16;
typedef unsigned int   u32;
typedef unsigned long long u64;
typedef __attribute__((ext_vector_type(2)))  u32  u32x2;
typedef __attribute__((ext_vector_type(4)))  float f32x4;
typedef __attribute__((ext_vector_type(16))) float f32x16;
typedef __attribute__((ext_vector_type(8)))  short b16x8;

#define T_ 256
#define B_ 32
#define V_ 32000
#define H_ 256

// fp32 -> bf16 round-to-nearest-even
__device__ __forceinline__ u16 f2bf(float f){
  union { float fv; u32 uv; } v; v.fv = f;
  return (u16)((v.uv + 0x7FFFu + ((v.uv >> 16) & 1u)) >> 16);
}
__device__ __forceinline__ float bf2f(short x){
  union { float fv; u32 uv; } c; c.uv = ((u32)(u16)x) << 16; return c.fv;
}
__device__ __forceinline__ float sigm_fast(float z){
  return __builtin_amdgcn_rcpf(1.0f + __builtin_amdgcn_exp2f(z * -1.44269504f));
}
// 16B agent-scope (cross-XCD coherent) load/store as 2x u64 atomics
__device__ __forceinline__ b16x8 ald16(const u16* p){
  union { u64 q[2]; b16x8 v; } u;
  const u64* q = (const u64*)p;
  u.q[0] = __hip_atomic_load(q,     __ATOMIC_RELAXED, __HIP_MEMORY_SCOPE_AGENT);
  u.q[1] = __hip_atomic_load(q + 1, __ATOMIC_RELAXED, __HIP_MEMORY_SCOPE_AGENT);
  return u.v;
}
__device__ __forceinline__ void ast16(u16* p, b16x8 v){
  union { u64 q[2]; b16x8 v; } u; u.v = v;
  u64* q = (u64*)p;
  __hip_atomic_store(q,     u.q[0], __ATOMIC_RELAXED, __HIP_MEMORY_SCOPE_AGENT);
  __hip_atomic_store(q + 1, u.q[1], __ATOMIC_RELAXED, __HIP_MEMORY_SCOPE_AGENT);
}

// ---------------------------------------------------------------------------
// prep (vectorized 8x, R12-verified): decW -> bf16 ; W^T copies ; flag reset
// ---------------------------------------------------------------------------
__global__ __launch_bounds__(256)
void prep_kernel(const float* __restrict__ Wi, const float* __restrict__ Wh,
                 const float* __restrict__ decW,
                 u16* __restrict__ decWb, u16* __restrict__ wt,
                 u32* __restrict__ flags){
  if (blockIdx.x == 0 && threadIdx.x == 0){ flags[0] = 0; flags[1] = 0; }
  const int NDECG = (V_ * H_) / 8;                 // 1,024,000
  const int NWTG  = (4 * H_ * H_) / 8;             //    32,768
  const int g = blockIdx.x * blockDim.x + threadIdx.x;
  if (g < NDECG){
    const float* s = decW + (size_t)g * 8;
    f32x4 a = *(const f32x4*)(s);
    f32x4 b = *(const f32x4*)(s + 4);
    union { u16 h[8]; b16x8 v; } o;
    #pragma unroll
    for (int u = 0; u < 4; ++u){
      o.h[u]     = f2bf(a[u]);
      o.h[4 + u] = f2bf(b[u]);
    }
    *(b16x8*)(decWb + (size_t)g * 8) = o.v;
  } else if (g < NDECG + NWTG){
    const int j0 = (g - NDECG) * 8;
    const int m  = j0 >> 16;
    const int r  = j0 & 65535;
    const int row = r >> 8;
    const int k0  = r & 255;
    const float* src = (m == 0) ? Wh
                     : (m == 1) ? (Wi + H_ * H_)
                     : (m == 2) ? (Wh + H_ * H_)
                     :            Wi;
    union { u16 h[8]; b16x8 v; } o;
    #pragma unroll
    for (int u = 0; u < 8; ++u)
      o.h[u] = f2bf(src[(k0 + u) * H_ + row]);
    *(b16x8*)(wt + j0) = o.v;
  }
}

// xp layout (R8/R10-verified, matches swapped consumers):
//   x[t][batch m][col n] at xp[t*8192 + (m>>4)*4096 + (n>>2)*64 + (m&15)*4 + (n&3)]

// ---------------------------------------------------------------------------
// x0: swapped-operand form (R8/R10-verified). Block = one step t; 4 waves.
// ---------------------------------------------------------------------------
__global__ __launch_bounds__(256, 2)
void x0_kernel(const int* __restrict__ ids, const float* __restrict__ emb,
               const u16* __restrict__ WiT0, const float* __restrict__ bh,
               float* __restrict__ xp){
  const int tid = threadIdx.x, w = tid >> 6, l = tid & 63;
  const int lr = l & 15, lh = l >> 4;
  const int t = blockIdx.x;

  b16x8 wA[4][8];
  #pragma unroll
  for (int nt = 0; nt < 4; ++nt){
    const int col = w * 64 + nt * 16 + lr;
    #pragma unroll
    for (int ks = 0; ks < 8; ++ks)
      wA[nt][ks] = *(const b16x8*)(WiT0 + (size_t)col * H_ + ks * 32 + lh * 8);
  }

  const int b0 = ids[t * B_ + lr];
  const int b1 = ids[t * B_ + 16 + lr];
  const float* er0 = emb + (size_t)b0 * H_;
  const float* er1 = emb + (size_t)b1 * H_;

  f32x4 acc[2][4];
  #pragma unroll
  for (int nt = 0; nt < 4; ++nt){
    f32x4 bs = *(const f32x4*)(bh + w * 64 + nt * 16 + lh * 4);
    acc[0][nt] = bs;
    acc[1][nt] = bs;
  }

  #pragma unroll
  for (int ks = 0; ks < 8; ++ks){
    b16x8 e[2];
    {
      f32x4 a0 = *(const f32x4*)(er0 + ks * 32 + lh * 8);
      f32x4 a1 = *(const f32x4*)(er0 + ks * 32 + lh * 8 + 4);
      f32x4 c0 = *(const f32x4*)(er1 + ks * 32 + lh * 8);
      f32x4 c1 = *(const f32x4*)(er1 + ks * 32 + lh * 8 + 4);
      #pragma unroll
      for (int i2 = 0; i2 < 4; ++i2){
        e[0][i2] = (short)f2bf(a0[i2]); e[0][4 + i2] = (short)f2bf(a1[i2]);
        e[1][i2] = (short)f2bf(c0[i2]); e[1][4 + i2] = (short)f2bf(c1[i2]);
      }
    }
    #pragma unroll
    for (int nt = 0; nt < 4; ++nt){
      acc[0][nt] = __builtin_amdgcn_mfma_f32_16x16x32_bf16(wA[nt][ks], e[0], acc[0][nt], 0, 0, 0);
      acc[1][nt] = __builtin_amdgcn_mfma_f32_16x16x32_bf16(wA[nt][ks], e[1], acc[1][nt], 0, 0, 0);
    }
  }
  #pragma unroll
  for (int mt = 0; mt < 2; ++mt)
    #pragma unroll
    for (int nt = 0; nt < 4; ++nt)
      *(f32x4*)(xp + (size_t)t * 8192 + mt * 4096 + w * 1024 + nt * 256 + lh * 64 + lr * 4)
          = acc[mt][nt];
}

// ---------------------------------------------------------------------------
// mega: blocks 0-1 = rec (RELAXED publish every 2 steps — visibility comes
// from the per-step barrier's vmcnt(0) drain of the sc1 stores, not from a
// fence); blocks 2..4001 = dec (distance-aware spin backoff).
// R13 configuration — best measured (415.6 us).
// ---------------------------------------------------------------------------
__global__ __launch_bounds__(512, 1)
void mega_kernel(const u16* __restrict__ wt, const float* __restrict__ xp,
                 const float* __restrict__ bh,
                 u16* __restrict__ outseq, float* __restrict__ hid,
                 const u16* __restrict__ decWb, const float* __restrict__ decB,
                 float* __restrict__ out, u32* __restrict__ flags){
  __shared__ u16 smu[65536];                        // 128 KiB union
  char* smem = (char*)smu;
  const int tid = threadIdx.x, w = tid >> 6, l = tid & 63;
  const int bid = blockIdx.x;

  if (bid < 2){
    // =============== rec: both layers, batch rows [bid*16, +16) ===========
    const int lr = l & 15, lh = l >> 4;

    const u16* whT0 = wt;
    const u16* wiT1 = wt + 65536;
    const u16* whT1 = wt + 131072;

    b16x8 wH0[2][8], wI1[2][8], wH1[2][8];
    #pragma unroll
    for (int nt = 0; nt < 2; ++nt){
      const int col = w * 32 + nt * 16 + lr;
      #pragma unroll
      for (int ks = 0; ks < 8; ++ks){
        wH0[nt][ks] = *(const b16x8*)(whT0 + (size_t)col * H_ + ks * 32 + lh * 8);
        wI1[nt][ks] = *(const b16x8*)(wiT1 + (size_t)col * H_ + ks * 32 + lh * 8);
        wH1[nt][ks] = *(const b16x8*)(whT1 + (size_t)col * H_ + ks * 32 + lh * 8);
      }
    }
    f32x4 bs1[2];
    #pragma unroll
    for (int nt = 0; nt < 2; ++nt)
      bs1[nt] = *(const f32x4*)(bh + H_ + w * 32 + nt * 16 + lh * 4);

    int ra[8];
    #pragma unroll
    for (int ks = 0; ks < 8; ++ks)
      ra[ks] = lr * 512 + ((ks * 64 + lh * 16) ^ ((lr & 7) << 4));

    int wrh[2];
    #pragma unroll
    for (int nt = 0; nt < 2; ++nt)
      wrh[nt] = lr * 512 + ((w * 64 + nt * 32 + lh * 8) ^ ((lr & 7) << 4));

    const int srow = tid >> 5, scolb = (tid & 31) * 16;
    const int sa = srow * 512 + (scolb ^ ((srow & 7) << 4));
    const size_t sgbase = (size_t)(bid * 16 + srow) * H_ + (tid & 31) * 8;

    const int xoff = bid * 4096 + w * 512 + lh * 64 + lr * 4;

    { u32* z = (u32*)smem;
      for (int i = tid; i < 8192; i += 512) z[i] = 0; }   // h0[-1], h1[-1] = 0

    f32x4 xc0, xc1, xn0, xn1;
    xc0 = *(const f32x4*)(xp + xoff);
    xc1 = *(const f32x4*)(xp + xoff + 256);
    __syncthreads();

#define PACKW(DST, ADDR, V0, V1, V2, V3)                                        \
  { u32x2 pk;                                                                   \
    pk[0] = (u32)f2bf(V0) | ((u32)f2bf(V1) << 16);                              \
    pk[1] = (u32)f2bf(V2) | ((u32)f2bf(V3) << 16);                              \
    *(u32x2*)((DST) + (ADDR)) = pk; }

#define STEP(PAR, S)                                                            \
  {                                                                             \
    const char* rb0 = smem + (PAR) * 8192;                                      \
    const char* rb1 = smem + 16384 + (1 - (PAR)) * 8192;                        \
    if ((S) >= 2){                                                              \
      b16x8 v = *(const b16x8*)(rb1 + sa);                                      \
      ast16(outseq + (size_t)((S) - 2) * 8192 + sgbase, v);                     \
    }                                                                           \
    f32x4 c0 = (f32x4){}, c1 = (f32x4){};                                       \
    f32x4 d0 = bs1[0], d1 = bs1[1];                                             \
    _Pragma("unroll")                                                           \
    for (int ks = 0; ks < 8; ++ks){                                             \
      b16x8 a = *(const b16x8*)(rb0 + ra[ks]);                                  \
      c0 = __builtin_amdgcn_mfma_f32_16x16x32_bf16(wH0[0][ks], a, c0, 0, 0, 0); \
      c1 = __builtin_amdgcn_mfma_f32_16x16x32_bf16(wH0[1][ks], a, c1, 0, 0, 0); \
      d0 = __builtin_amdgcn_mfma_f32_16x16x32_bf16(wI1[0][ks], a, d0, 0, 0, 0); \
      d1 = __builtin_amdgcn_mfma_f32_16x16x32_bf16(wI1[1][ks], a, d1, 0, 0, 0); \
    }                                                                           \
    { const float* pn = xp + (size_t)(((S) < 255) ? (S) + 1 : 255) * 8192 + xoff; \
      xn0 = *(const f32x4*)(pn);                                                \
      xn1 = *(const f32x4*)(pn + 256); }                                        \
    { char* wb0 = smem + (1 - (PAR)) * 8192;                                    \
      PACKW(wb0, wrh[0], sigm_fast(c0[0] + xc0[0]), sigm_fast(c0[1] + xc0[1]),  \
                         sigm_fast(c0[2] + xc0[2]), sigm_fast(c0[3] + xc0[3]))  \
      PACKW(wb0, wrh[1], sigm_fast(c1[0] + xc1[0]), sigm_fast(c1[1] + xc1[1]),  \
                         sigm_fast(c1[2] + xc1[2]), sigm_fast(c1[3] + xc1[3]))  \
    }                                                                           \
    if ((S) >= 1){                                                              \
      _Pragma("unroll")                                                         \
      for (int ks = 0; ks < 8; ++ks){                                           \
        b16x8 a = *(const b16x8*)(rb1 + ra[ks]);                                \
        d0 = __builtin_amdgcn_mfma_f32_16x16x32_bf16(wH1[0][ks], a, d0, 0, 0, 0); \
        d1 = __builtin_amdgcn_mfma_f32_16x16x32_bf16(wH1[1][ks], a, d1, 0, 0, 0); \
      }                                                                         \
      char* wb1 = smem + 16384 + (PAR) * 8192;                                  \
      PACKW(wb1, wrh[0], sigm_fast(d0[0]), sigm_fast(d0[1]),                    \
                         sigm_fast(d0[2]), sigm_fast(d0[3]))                    \
      PACKW(wb1, wrh[1], sigm_fast(d1[0]), sigm_fast(d1[1]),                    \
                         sigm_fast(d1[2]), sigm_fast(d1[3]))                    \
    }                                                                           \
    xc0 = xn0; xc1 = xn1;                                                       \
    __syncthreads();                                                            \
  }

    for (int s2 = 0; s2 < 128; ++s2){
      const int s = s2 * 2;
      STEP(0, s)
      STEP(1, s + 1)
      // after the barrier (vmcnt(0) drained), steps < 2*s2 are globally
      // visible via sc1 -> RELAXED publish is sufficient (no fence).
      if (tid == 0)
        __hip_atomic_store(&flags[bid], (u32)(s2 * 2), __ATOMIC_RELAXED,
                           __HIP_MEMORY_SCOPE_AGENT);
    }
#undef STEP

    // epilogue: h0[255] in h0 buf0; h1[254] in h1 buf1; compute h1[255]
    {
      { b16x8 v = *(const b16x8*)(smem + 16384 + 8192 + sa);
        ast16(outseq + (size_t)254 * 8192 + sgbase, v); }

      f32x4 d0 = bs1[0], d1 = bs1[1];
      #pragma unroll
      for (int ks = 0; ks < 8; ++ks){
        b16x8 a0 = *(const b16x8*)(smem + ra[ks]);
        b16x8 a1 = *(const b16x8*)(smem + 16384 + 8192 + ra[ks]);
        d0 = __builtin_amdgcn_mfma_f32_16x16x32_bf16(wI1[0][ks], a0, d0, 0, 0, 0);
        d1 = __builtin_amdgcn_mfma_f32_16x16x32_bf16(wI1[1][ks], a0, d1, 0, 0, 0);
        d0 = __builtin_amdgcn_mfma_f32_16x16x32_bf16(wH1[0][ks], a1, d0, 0, 0, 0);
        d1 = __builtin_amdgcn_mfma_f32_16x16x32_bf16(wH1[1][ks], a1, d1, 0, 0, 0);
      }
      { char* wb1 = smem + 16384;
        PACKW(wb1, wrh[0], sigm_fast(d0[0]), sigm_fast(d0[1]),
                           sigm_fast(d0[2]), sigm_fast(d0[3]))
        PACKW(wb1, wrh[1], sigm_fast(d1[0]), sigm_fast(d1[1]),
                           sigm_fast(d1[2]), sigm_fast(d1[3]))
      }
      __syncthreads();

      b16x8 h1v = *(const b16x8*)(smem + 16384 + sa);
      b16x8 h0v = *(const b16x8*)(smem + sa);
      ast16(outseq + (size_t)255 * 8192 + sgbase, h1v);
      float* hd0 = hid + sgbase;
      float* hd1 = hid + 8192 + sgbase;
      #pragma unroll
      for (int j = 0; j < 8; ++j){
        hd0[j] = bf2f(h0v[j]);
        hd1[j] = bf2f(h1v[j]);
      }
      __syncthreads();                // drains the final ast16 stores (vmcnt 0)
      if (tid == 0)
        __hip_atomic_store(&flags[bid], 256u, __ATOMIC_RELAXED,
                           __HIP_MEMORY_SCOPE_AGENT);
    }
#undef PACKW
  } else {
    // =============== dec: decoded = outseq @ decW^T + decB ================
    const int la = l & 31, hi = l >> 5;
    const int wm = w >> 2, wn = w & 3;

    const int idx = bid - 2;
    const int mb  = idx / 125;                      // mb-major dispatch order
    const int nb  = idx - mb * 125;

    // wait until outseq rows [mb*256, +256) (steps [mb*8, mb*8+8)) published
    if (tid == 0){
      const u32 need = (u32)(mb * 8 + 8);
      const u64* fl = (const u64*)flags;
      for (;;){
        u64 ff = __hip_atomic_load(fl, __ATOMIC_RELAXED, __HIP_MEMORY_SCOPE_AGENT);
        u32 f0 = (u32)ff, f1 = (u32)(ff >> 32);
        u32 got = f0 < f1 ? f0 : f1;
        if (got >= need) break;
        if (need - got > 24) __builtin_amdgcn_s_sleep(64);
        else                 __builtin_amdgcn_s_sleep(8);
      }
    }
    __syncthreads();

    const int srow = tid >> 3;
    const int sc   = tid & 7;
    const int scx  = sc ^ (srow & 7);
    const size_t gA = ((size_t)(mb * 256 + srow)) * H_ + sc * 8;
    const size_t gB = ((size_t)(nb * 256 + srow)) * H_ + sc * 8;
    const int    sl = srow * 128 + scx * 16;

    b16x8 rA[4], rB[4];
#define GLOADS(KK)                                                              \
  { _Pragma("unroll")                                                           \
    for (int s5 = 0; s5 < 4; ++s5){                                             \
      rA[s5] = ald16(outseq + gA + (size_t)s5 * 64 * H_ + (KK) * 64);           \
      rB[s5] = *(const b16x8*)(decWb + gB + (size_t)s5 * 64 * H_ + (KK) * 64);  \
    } }
#define DSWRITE(BUF)                                                            \
  { _Pragma("unroll")                                                           \
    for (int s5 = 0; s5 < 4; ++s5){                                             \
      *(b16x8*)(smem + (BUF) * 32768 + s5 * 8192 + sl)         = rA[s5];        \
      *(b16x8*)(smem + 65536 + (BUF) * 32768 + s5 * 8192 + sl) = rB[s5];        \
    } }

    const int aRow = wm * 128 + la;
    const int bRow = wn * 64 + la;
    int fOff[4];
    #pragma unroll
    for (int ks = 0; ks < 4; ++ks)
      fOff[ks] = ((ks * 32 + hi * 16) ^ ((la & 7) << 4));

    f32x16 acc[4][2];
    #pragma unroll
    for (int mt = 0; mt < 4; ++mt)
      #pragma unroll
      for (int nt = 0; nt < 2; ++nt)
        acc[mt][nt] = (f32x16){};

    GLOADS(0);
    #pragma unroll
    for (int kk = 0; kk < 4; ++kk){
      DSWRITE(kk & 1);
      if (kk < 3) GLOADS(kk + 1);
      __syncthreads();
      const char* bufA = smem + (kk & 1) * 32768;
      const char* bufB = smem + 65536 + (kk & 1) * 32768;
      #pragma unroll
      for (int ks = 0; ks < 4; ++ks){
        b16x8 aF[4], bF[2];
        #pragma unroll
        for (int mt = 0; mt < 4; ++mt)
          aF[mt] = *(const b16x8*)(bufA + (aRow + mt * 32) * 128 + fOff[ks]);
        #pragma unroll
        for (int nt = 0; nt < 2; ++nt)
          bF[nt] = *(const b16x8*)(bufB + (bRow + nt * 32) * 128 + fOff[ks]);
        #pragma unroll
        for (int mt = 0; mt < 4; ++mt)
          #pragma unroll
          for (int nt = 0; nt < 2; ++nt)
            acc[mt][nt] = __builtin_amdgcn_mfma_f32_32x32x16_bf16(aF[mt], bF[nt], acc[mt][nt], 0, 0, 0);
      }
      __syncthreads();
    }
#undef GLOADS
#undef DSWRITE

    #pragma unroll
    for (int nt = 0; nt < 2; ++nt){
      const int colg = nb * 256 + wn * 64 + nt * 32 + la;
      const float bias = decB[colg];
      #pragma unroll
      for (int mt = 0; mt < 4; ++mt){
        const int rowb = mb * 256 + wm * 128 + mt * 32 + hi * 4;
        #pragma unroll
        for (int r = 0; r < 16; ++r){
          const int rowg = rowb + (r & 3) + 8 * (r >> 2);
          __builtin_nontemporal_store(acc[mt][nt][r] + bias,
                                      &out[(size_t)rowg * V_ + colg]);
        }
      }
    }
  }
}

// ---------------------------------------------------------------------------
extern "C" void kernel_launch(void* const* d_in, const int* in_sizes, int n_in,
                              void* d_out, int out_size, void* d_ws, size_t ws_size,
                              hipStream_t stream){
  const int*   ids  = (const int*)  d_in[0];
  const float* emb  = (const float*)d_in[1];
  const float* Wi   = (const float*)d_in[2];
  const float* Wh   = (const float*)d_in[3];
  const float* bh   = (const float*)d_in[4];
  const float* decW = (const float*)d_in[5];
  const float* decB = (const float*)d_in[6];
  float* out = (float*)d_out;

  char* ws = (char*)d_ws;
  u16*  decWb  = (u16*)(ws);                       // 16,384,000 B
  u16*  wt     = (u16*)(ws + 16384000);            //    524,288 B
  u16*  outseq = (u16*)(ws + 16908288);            //  4,194,304 B
  float* xp    = (float*)(ws + 21102592);          //  8,388,608 B
  u32*  flags  = (u32*)(ws + 29491200);            //          8 B

  float* hid = out + (size_t)T_ * B_ * V_;         // [L][B][H] fp32 tail of d_out

  prep_kernel<<<4128, 256, 0, stream>>>(Wi, Wh, decW, decWb, wt, flags);
  x0_kernel<<<256, 256, 0, stream>>>(ids, emb, wt + 3 * H_ * H_, bh, xp);
  mega_kernel<<<4002, 512, 0, stream>>>(wt, xp, bh, outseq, hid,
                                        decWb, decB, out, flags);
}